// Round 1
// 227.196 us; speedup vs baseline: 1.0611x; 1.0611x over previous
//
#include <hip/hip_runtime.h>

// Problem constants: B=4, C=3, H=512, W=960, K2=16 -> K=4
#define BB 4
#define CC 3
#define HH 512
#define WW 960
#define HW (HH * WW)
#define NPIX (BB * HW)

// 2D tiling: 64x4 pixels per 256-thread block
#define TW 64
#define TH 4
#define NTX (WW / TW)          // 15
#define NTY (HH / TH)          // 128
#define NBLK (BB * NTX * NTY)  // 7680

// Staged input tile: rows y0-5 .. y0+10 (16), cols x0-8 .. x0+71 (80), 3 ch.
// Tolerates |fy| <= 4, |fx| <= 5 for every pixel in the tile (N(0,1) flow:
// out-of-tile probability ~1e-9/pixel; global fallback path covers it).
#define ROWS 16
#define COLS 80
#define CPAD 84                 // padded col stride (floats) to decorrelate banks
#define LDS_FLOATS (ROWS * CC * CPAD)   // 4032 floats = 16128 B

__global__ __launch_bounds__(256)
void filter_interp_kernel(const float* __restrict__ inp,
                          const float* __restrict__ flow,
                          const float* __restrict__ filt,
                          float* __restrict__ out) {
    __shared__ float lds[LDS_FLOATS];

    // Bijective XCD-aware swizzle (NBLK % 8 == 0): each XCD gets a contiguous
    // chunk of ty-fastest tiles -> vertical strips, input slice ~3MB fits L2.
    const int bid = blockIdx.x;
    const int swz = (bid & 7) * (NBLK / 8) + (bid >> 3);
    const int b   = swz / (NTX * NTY);
    const int rr  = swz - b * (NTX * NTY);
    const int tx  = rr / NTY;
    const int ty  = rr - tx * NTY;
    const int x0  = tx * TW;
    const int y0  = ty * TH;

    const int tid = threadIdx.x;
    const float* ibase = inp + (size_t)b * CC * HW;

    // ---- Stage input tile into LDS (clamped rows/cols baked in) ----
    if (tx > 0 && tx < NTX - 1) {
        // Interior in x: cols x0-8 .. x0+71 all in-range and 16B-aligned.
#pragma unroll
        for (int e = 0; e < 4; ++e) {
            const int idx = e * 256 + tid;
            if (idx < ROWS * CC * (COLS / 4)) {          // 960 float4s
                const int s  = idx / (CC * (COLS / 4));  // /60
                const int r2 = idx - s * (CC * (COLS / 4));
                const int ch = r2 / (COLS / 4);          // /20
                const int t4 = r2 - ch * (COLS / 4);
                const int grow = min(max(y0 - 5 + s, 0), HH - 1);
                const float4 v = *(const float4*)(ibase + (size_t)ch * HW +
                                                  (size_t)grow * WW +
                                                  (x0 - 8 + t4 * 4));
                *(float4*)&lds[(s * CC + ch) * CPAD + t4 * 4] = v;
            }
        }
    } else {
        // x-edge tile: scalar loads with per-column clamp.
#pragma unroll
        for (int e = 0; e < 15; ++e) {
            const int idx = e * 256 + tid;               // exactly 3840 total
            const int s  = idx / (CC * COLS);            // /240
            const int r2 = idx - s * (CC * COLS);
            const int ch = r2 / COLS;
            const int t  = r2 - ch * COLS;
            const int grow = min(max(y0 - 5 + s, 0), HH - 1);
            const int gcol = min(max(x0 - 8 + t, 0), WW - 1);
            lds[(s * CC + ch) * CPAD + t] =
                ibase[(size_t)ch * HW + (size_t)grow * WW + gcol];
        }
    }

    // ---- Hoist flow + filter loads so they fly across the barrier ----
    const int lx = tid & (TW - 1);
    const int wy = tid >> 6;
    const int x  = x0 + lx;
    const int y  = y0 + wy;
    const int rem = y * WW + x;

    const float fx = flow[(size_t)(b * 2 + 0) * HW + rem];
    const float fy = flow[(size_t)(b * 2 + 1) * HW + rem];

    float f[16];
    {
        const float* fptr = filt + (size_t)b * 16 * HW + rem;
#pragma unroll
        for (int k = 0; k < 16; ++k) f[k] = fptr[(size_t)k * HW];
    }

    __syncthreads();

    const float x2 = (float)x + fx;
    const float y2 = (float)y + fy;

    const bool valid = (x2 >= 0.0f) && (x2 <= (float)(WW - 1)) &&
                       (y2 >= 0.0f) && (y2 <= (float)(HH - 1)) &&
                       (fabsf(fx) < (float)WW * 0.5f) &&
                       (fabsf(fy) < (float)HH * 0.5f);

    float acc0 = 0.0f, acc1 = 0.0f, acc2 = 0.0f;

    if (valid) {
        const int ix = (int)floorf(x2);
        const int iy = (int)floorf(y2);
        const float alpha = x2 - (float)ix;
        const float beta  = y2 - (float)iy;

        const float wTL = (1.0f - alpha) * (1.0f - beta);
        const float wTR = alpha * (1.0f - beta);
        const float wBL = (1.0f - alpha) * beta;
        const float wBR = alpha * beta;

        // Fold 16 taps x 4 bilinear weights into 5x5 (channel-independent).
        float Wm[5][5];
#pragma unroll
        for (int j = 0; j < 5; ++j)
#pragma unroll
            for (int i = 0; i < 5; ++i) Wm[j][i] = 0.0f;
#pragma unroll
        for (int dj = 0; dj < 4; ++dj) {
#pragma unroll
            for (int di = 0; di < 4; ++di) {
                const float fv = f[dj * 4 + di];
                Wm[dj][di]         += fv * wTL;
                Wm[dj][di + 1]     += fv * wTR;
                Wm[dj + 1][di]     += fv * wBL;
                Wm[dj + 1][di + 1] += fv * wBR;
            }
        }

        const int ixL0 = ix - 1;
        const int iyT0 = iy - 1;
        const int cs = ixL0 - (x0 - 8);   // col slot of window start
        const int rs = iyT0 - (y0 - 5);   // row slot of window start

        if ((unsigned)rs <= (unsigned)(ROWS - 5) &&
            (unsigned)cs <= (unsigned)(COLS - 5)) {
            // Fast path: 5x5x3 gather from LDS. Slot contents are already
            // border-clamped, so no per-tap clamping and no alignment games.
            const float* lbase = &lds[rs * (CC * CPAD) + cs];
#pragma unroll
            for (int j = 0; j < 5; ++j) {
                const float* lr = lbase + j * (CC * CPAD);
#pragma unroll
                for (int i = 0; i < 5; ++i) {
                    const float w = Wm[j][i];
                    acc0 += lr[i] * w;
                    acc1 += lr[CPAD + i] * w;
                    acc2 += lr[2 * CPAD + i] * w;
                }
            }
        } else {
            // Rare fallback (|flow| beyond tile margin but still valid):
            // scalar clamped global gathers, same math as verified slow path.
            int R[5], S[5];
#pragma unroll
            for (int j = 0; j < 5; ++j) R[j] = min(max(iyT0 + j, 0), HH - 1);
#pragma unroll
            for (int i = 0; i < 5; ++i) S[i] = min(max(ixL0 + i, 0), WW - 1);
#pragma unroll
            for (int j = 0; j < 5; ++j) {
                const float* r0 = ibase + (size_t)R[j] * WW;
#pragma unroll
                for (int i = 0; i < 5; ++i) {
                    const float w = Wm[j][i];
                    const size_t o = (size_t)S[i];
                    acc0 += r0[o] * w;
                    acc1 += r0[HW + o] * w;
                    acc2 += r0[2 * (size_t)HW + o] * w;
                }
            }
        }
    }

    const int outbase = b * CC * HW + rem;
    out[outbase]          = acc0;
    out[outbase + HW]     = acc1;
    out[outbase + 2 * HW] = acc2;
}

extern "C" void kernel_launch(void* const* d_in, const int* in_sizes, int n_in,
                              void* d_out, int out_size, void* d_ws, size_t ws_size,
                              hipStream_t stream) {
    const float* teninput  = (const float*)d_in[0];
    const float* tenflow   = (const float*)d_in[1];
    const float* tenfilter = (const float*)d_in[2];
    float* out = (float*)d_out;

    filter_interp_kernel<<<NBLK, 256, 0, stream>>>(teninput, tenflow, tenfilter, out);
}

// Round 2
// 220.374 us; speedup vs baseline: 1.0939x; 1.0310x over previous
//
#include <hip/hip_runtime.h>

// Problem constants: B=4, C=3, H=512, W=960, K2=16 -> K=4
#define BB 4
#define CC 3
#define HH 512
#define WW 960
#define HW (HH * WW)
#define NPIX (BB * HW)

// 2D tiling: 64x4 pixels per 256-thread block
#define TW 64
#define TH 4
#define NTX (WW / TW)          // 15
#define NTY (HH / TH)          // 128
#define NBLK (BB * NTX * NTY)  // 7680

// Staged input tile: rows y0-5 .. y0+10 (16), cols x0-8 .. x0+71 (80), 3 ch.
// Layout [s][ch][t], UNPADDED stride 80 -> linear in load index, so interior
// staging can use global_load_lds (wave-uniform base + lane*16B).
// Gather lanes differ by 1 column -> 2 lanes/bank = free, no pad needed.
#define ROWS 16
#define COLS 80
#define RSTRIDE (CC * COLS)             // 240 floats per staged row
#define LDS_FLOATS (ROWS * RSTRIDE)     // 3840 floats = 15360 B

typedef __attribute__((address_space(1))) const unsigned int gu32;
typedef __attribute__((address_space(3))) unsigned int lu32;

__global__ __launch_bounds__(256)
void filter_interp_kernel(const float* __restrict__ inp,
                          const float* __restrict__ flow,
                          const float* __restrict__ filt,
                          float* __restrict__ out) {
    __shared__ float lds[LDS_FLOATS];

    // Bijective XCD-aware swizzle (NBLK % 8 == 0): ty-fastest -> each XCD
    // works a contiguous vertical strip; input slice fits its L2.
    const int bid = blockIdx.x;
    const int swz = (bid & 7) * (NBLK / 8) + (bid >> 3);
    const int b   = swz / (NTX * NTY);
    const int rr  = swz - b * (NTX * NTY);
    const int tx  = rr / NTY;
    const int ty  = rr - tx * NTY;
    const int x0  = tx * TW;
    const int y0  = ty * TH;

    const int tid  = threadIdx.x;
    const int wave = tid >> 6;
    const float* ibase = inp + (size_t)b * CC * HW;

    // ---- Stage input tile into LDS ----
    if (tx > 0 && tx < NTX - 1) {
        // Interior in x: async DMA straight to LDS, no VGPR round-trip.
        // lds float offset of element idx is exactly idx*4 (layout is linear),
        // dest = wave-uniform base + lane*16B as required.
#pragma unroll
        for (int e = 0; e < 4; ++e) {
            const int idx = e * 256 + tid;
            if (idx < ROWS * CC * (COLS / 4)) {          // 960 float4s
                const int s  = idx / 60;                 // CC*(COLS/4)
                const int r2 = idx - s * 60;
                const int ch = r2 / 20;                  // COLS/4
                const int t4 = r2 - ch * 20;
                const int grow = min(max(y0 - 5 + s, 0), HH - 1);
                const float* src = ibase + (size_t)ch * HW +
                                   (size_t)grow * WW + (x0 - 8 + t4 * 4);
                lu32* dst = (lu32*)(void*)&lds[(e * 256 + wave * 64) * 4];
                __builtin_amdgcn_global_load_lds((gu32*)(const void*)src,
                                                 dst, 16, 0, 0);
            }
        }
    } else {
        // x-edge tile: scalar loads with per-column clamp (layout is linear,
        // so lds[idx] is the right slot).
#pragma unroll
        for (int e = 0; e < 15; ++e) {
            const int idx = e * 256 + tid;               // exactly 3840 total
            const int s  = idx / RSTRIDE;
            const int r2 = idx - s * RSTRIDE;
            const int ch = r2 / COLS;
            const int t  = r2 - ch * COLS;
            const int grow = min(max(y0 - 5 + s, 0), HH - 1);
            const int gcol = min(max(x0 - 8 + t, 0), WW - 1);
            lds[idx] = ibase[(size_t)ch * HW + (size_t)grow * WW + gcol];
        }
    }

    // ---- Hoist flow + filter loads so they fly across the barrier ----
    const int lx = tid & (TW - 1);
    const int wy = tid >> 6;
    const int x  = x0 + lx;
    const int y  = y0 + wy;
    const int rem = y * WW + x;

    const float fx = flow[(size_t)(b * 2 + 0) * HW + rem];
    const float fy = flow[(size_t)(b * 2 + 1) * HW + rem];

    float f[16];
    {
        const float* fptr = filt + (size_t)b * 16 * HW + rem;
#pragma unroll
        for (int k = 0; k < 16; ++k) f[k] = fptr[(size_t)k * HW];
    }

    __syncthreads();   // vmcnt(0) here also drains the global_load_lds DMA

    const float x2 = (float)x + fx;
    const float y2 = (float)y + fy;

    const bool valid = (x2 >= 0.0f) && (x2 <= (float)(WW - 1)) &&
                       (y2 >= 0.0f) && (y2 <= (float)(HH - 1)) &&
                       (fabsf(fx) < (float)WW * 0.5f) &&
                       (fabsf(fy) < (float)HH * 0.5f);

    float acc0 = 0.0f, acc1 = 0.0f, acc2 = 0.0f;

    if (valid) {
        const int ix = (int)floorf(x2);
        const int iy = (int)floorf(y2);
        const float alpha = x2 - (float)ix;
        const float beta  = y2 - (float)iy;

        const float wTL = (1.0f - alpha) * (1.0f - beta);
        const float wTR = alpha * (1.0f - beta);
        const float wBL = (1.0f - alpha) * beta;
        const float wBR = alpha * beta;

        // Fold 16 taps x 4 bilinear weights into 5x5 (channel-independent).
        float Wm[5][5];
#pragma unroll
        for (int j = 0; j < 5; ++j)
#pragma unroll
            for (int i = 0; i < 5; ++i) Wm[j][i] = 0.0f;
#pragma unroll
        for (int dj = 0; dj < 4; ++dj) {
#pragma unroll
            for (int di = 0; di < 4; ++di) {
                const float fv = f[dj * 4 + di];
                Wm[dj][di]         += fv * wTL;
                Wm[dj][di + 1]     += fv * wTR;
                Wm[dj + 1][di]     += fv * wBL;
                Wm[dj + 1][di + 1] += fv * wBR;
            }
        }

        const int ixL0 = ix - 1;
        const int iyT0 = iy - 1;
        const int cs = ixL0 - (x0 - 8);   // col slot of window start
        const int rs = iyT0 - (y0 - 5);   // row slot of window start

        if ((unsigned)rs <= (unsigned)(ROWS - 5) &&
            (unsigned)cs <= (unsigned)(COLS - 5)) {
            // Fast path: b64 gather. Window aligned down to even column e0;
            // 3 float2 reads per row/channel cover taps cs..cs+4. Weight row
            // barrel-shifted by o = cs&1 into a 6-wide row (one-time selects).
            const int o  = cs & 1;
            const int e0 = cs - o;
            const float* lbase = &lds[rs * RSTRIDE + e0];
#pragma unroll
            for (int j = 0; j < 5; ++j) {
                const float* lr = lbase + j * RSTRIDE;
                const float w0 = o ? 0.0f     : Wm[j][0];
                const float w1 = o ? Wm[j][0] : Wm[j][1];
                const float w2 = o ? Wm[j][1] : Wm[j][2];
                const float w3 = o ? Wm[j][2] : Wm[j][3];
                const float w4 = o ? Wm[j][3] : Wm[j][4];
                const float w5 = o ? Wm[j][4] : 0.0f;

                const float2 a0 = *(const float2*)(lr);
                const float2 a1 = *(const float2*)(lr + 2);
                const float2 a2 = *(const float2*)(lr + 4);
                acc0 += a0.x * w0 + a0.y * w1 + a1.x * w2 +
                        a1.y * w3 + a2.x * w4 + a2.y * w5;

                const float2 b0 = *(const float2*)(lr + COLS);
                const float2 b1 = *(const float2*)(lr + COLS + 2);
                const float2 b2 = *(const float2*)(lr + COLS + 4);
                acc1 += b0.x * w0 + b0.y * w1 + b1.x * w2 +
                        b1.y * w3 + b2.x * w4 + b2.y * w5;

                const float2 c0 = *(const float2*)(lr + 2 * COLS);
                const float2 c1 = *(const float2*)(lr + 2 * COLS + 2);
                const float2 c2 = *(const float2*)(lr + 2 * COLS + 4);
                acc2 += c0.x * w0 + c0.y * w1 + c1.x * w2 +
                        c1.y * w3 + c2.x * w4 + c2.y * w5;
            }
        } else {
            // Rare fallback (|flow| beyond tile margin but still valid):
            // scalar clamped global gathers, same math as verified slow path.
            int R[5], S[5];
#pragma unroll
            for (int j = 0; j < 5; ++j) R[j] = min(max(iyT0 + j, 0), HH - 1);
#pragma unroll
            for (int i = 0; i < 5; ++i) S[i] = min(max(ixL0 + i, 0), WW - 1);
#pragma unroll
            for (int j = 0; j < 5; ++j) {
                const float* r0 = ibase + (size_t)R[j] * WW;
#pragma unroll
                for (int i = 0; i < 5; ++i) {
                    const float w = Wm[j][i];
                    const size_t oidx = (size_t)S[i];
                    acc0 += r0[oidx] * w;
                    acc1 += r0[HW + oidx] * w;
                    acc2 += r0[2 * (size_t)HW + oidx] * w;
                }
            }
        }
    }

    const int outbase = b * CC * HW + rem;
    out[outbase]          = acc0;
    out[outbase + HW]     = acc1;
    out[outbase + 2 * HW] = acc2;
}

extern "C" void kernel_launch(void* const* d_in, const int* in_sizes, int n_in,
                              void* d_out, int out_size, void* d_ws, size_t ws_size,
                              hipStream_t stream) {
    const float* teninput  = (const float*)d_in[0];
    const float* tenflow   = (const float*)d_in[1];
    const float* tenfilter = (const float*)d_in[2];
    float* out = (float*)d_out;

    filter_interp_kernel<<<NBLK, 256, 0, stream>>>(teninput, tenflow, tenfilter, out);
}